// Round 7
// baseline (665.378 us; speedup 1.0000x reference)
//
#include <hip/hip_runtime.h>
#include <hip/hip_bf16.h>
#include <math.h>

// Laplacian-pyramid L1 loss, (2,1,64,256,256), 5 levels, sigma=1 (9-tap), scipy-reflect.
// loss = sum_l mean |lap_pyramid(input-target)[l]| (linearity of the pyramid).
// THREE dispatches:
//   1) k1l0  : level-0 WH-down of (in-tg) -> T1  (+ bf16 DIFF; zeroes sync ctrs)
//   2) dsall : whole downsample ladder in one launch, 8 producer/consumer stages
//              (co-residency by capacity: 930 blocks, >=4 blocks/CU guaranteed)
//   3) k4p   : all 4696 loss tiles (fused z-filter upsample + |cur-up| reduce),
//              last block (completion counter) does the final reduction.

struct GW { float w[9]; float A, B; };

__device__ __forceinline__ int ridx(int p, int n) {
    // scipy 'reflect' (symmetric) for power-of-two n; valid for p >= -2n
    int m = 2 * n;
    int q = (p + m) & (m - 1);
    return (q < n) ? q : (m - 1 - q);
}

__device__ __forceinline__ float block_sum256(float v) {
    #pragma unroll
    for (int off = 32; off > 0; off >>= 1) v += __shfl_down(v, off, 64);
    __shared__ float wp[4];
    int tid = threadIdx.x;
    if ((tid & 63) == 0) wp[tid >> 6] = v;
    __syncthreads();
    return wp[0] + wp[1] + wp[2] + wp[3];
}

// ---- producer/consumer sync (device scope; G16-safe) ----------------------
__device__ __forceinline__ void waitctr(unsigned int* c, unsigned int target) {
    if (threadIdx.x == 0) {
        while (__hip_atomic_load(c, __ATOMIC_ACQUIRE, __HIP_MEMORY_SCOPE_AGENT) < target)
            __builtin_amdgcn_s_sleep(8);
    }
    __syncthreads();
}
__device__ __forceinline__ void signalctr(unsigned int* c) {
    __threadfence();          // each thread drains its stores (release, device)
    __syncthreads();
    if (threadIdx.x == 0)
        __hip_atomic_fetch_add(c, 1u, __ATOMIC_RELEASE, __HIP_MEMORY_SCOPE_AGENT);
}

// ---------------------------------------------------------------------------
// k1l0: level-0 fused W+H gaussian of (in - tg), emitting even (y,x) -> T1.
// Optionally writes bf16 DIFF = in - tg. Tile 64x16 downsampled; grid (2,8,128).
template<bool WDIFF>
__global__ __launch_bounds__(256)
void k1l0(const float* __restrict__ in, const float* __restrict__ tg,
          float* __restrict__ T1, __hip_bfloat16* __restrict__ DIFF,
          unsigned int* __restrict__ ctr, GW g)
{
    if (blockIdx.x == 0 && blockIdx.y == 0 && blockIdx.z == 0 && threadIdx.x < 16)
        ctr[threadIdx.x] = 0;          // visible to dsall at kernel boundary
    const int H = 256, W = 256, Hd = 128, Wd = 128;
    const int x0d = blockIdx.x * 64, y0d = blockIdx.y * 16, slice = blockIdx.z;
    __shared__ float raw[40][136];
    __shared__ float mid[40][64];
    const size_t in_off  = (size_t)slice * H * W;
    const size_t out_off = (size_t)slice * Hd * Wd;
    const int tid = threadIdx.x;
    const int gy0 = 2*y0d - 4, gx0 = 2*x0d - 4;
    for (int i = tid; i < 40*32; i += 256) {
        int rr = i >> 5, c4 = (i & 31) + 1;
        int gy = ridx(gy0 + rr, H);
        size_t base = in_off + (size_t)gy * W + gx0 + 4*c4;
        float4 v = *(const float4*)(in + base);
        float4 b = *(const float4*)(tg + base);
        v.x -= b.x; v.y -= b.y; v.z -= b.z; v.w -= b.w;
        *(float4*)&raw[rr][4*c4] = v;
    }
    for (int i = tid; i < 40*8; i += 256) {
        int rr = i >> 3, j = i & 7;
        int cc = (j < 4) ? j : (128 + j);
        int gy = ridx(gy0 + rr, H);
        int gx = ridx(gx0 + cc, W);
        size_t idx = in_off + (size_t)gy * W + gx;
        raw[rr][cc] = in[idx] - tg[idx];
    }
    __syncthreads();
    if (WDIFF) {
        for (int i = tid; i < 32*128; i += 256) {
            int r = i >> 7, c = i & 127;
            DIFF[in_off + (size_t)(2*y0d + r) * W + (2*x0d + c)] =
                __float2bfloat16(raw[4 + r][4 + c]);
        }
    }
    for (int i = tid; i < 40*64; i += 256) {
        int rr = i >> 6, c = i & 63;
        float s = 0.f;
        #pragma unroll
        for (int k = 0; k < 9; ++k) s = fmaf(g.w[k], raw[rr][2*c + k], s);
        mid[rr][c] = s;
    }
    __syncthreads();
    {
        int r = tid >> 6, c = tid & 63;
        int ox = x0d + c;
        #pragma unroll
        for (int j = 0; j < 4; ++j) {
            int oy = y0d + r*4 + j;
            int rb = 2*(r*4 + j);
            float s = 0.f;
            #pragma unroll
            for (int k = 0; k < 9; ++k) s = fmaf(g.w[k], mid[rb + k][c], s);
            T1[out_off + (size_t)oy * Wd + ox] = s;
        }
    }
}

// ---------------------------------------------------------------------------
// dev_k2_elem: D-axis gaussian + batch(2) reflect mix at even z. One float4/elem.
__device__ void dev_k2_elem(long i, const float4* __restrict__ T, float4* __restrict__ O,
                            int D, int Dd, int M4, const GW& g)
{
    if (i >= (long)Dd * M4) return;
    int zd = (int)(i / M4);
    int q  = (int)(i - (long)zd * M4);
    float4 s0 = {0,0,0,0}, s1 = {0,0,0,0};
    #pragma unroll
    for (int k = 0; k < 9; ++k) {
        int zp = 2*zd - 4 + k;
        int zk = (zp >= 0 && zp < D) ? zp : ridx(zp, D);
        float4 a = T[(size_t)zk * M4 + q];
        float4 b = T[(size_t)(D + zk) * M4 + q];
        s0.x = fmaf(g.w[k], a.x, s0.x); s0.y = fmaf(g.w[k], a.y, s0.y);
        s0.z = fmaf(g.w[k], a.z, s0.z); s0.w = fmaf(g.w[k], a.w, s0.w);
        s1.x = fmaf(g.w[k], b.x, s1.x); s1.y = fmaf(g.w[k], b.y, s1.y);
        s1.z = fmaf(g.w[k], b.z, s1.z); s1.w = fmaf(g.w[k], b.w, s1.w);
    }
    float4 o0, o1;
    o0.x = g.A*s0.x + g.B*s1.x; o0.y = g.A*s0.y + g.B*s1.y;
    o0.z = g.A*s0.z + g.B*s1.z; o0.w = g.A*s0.w + g.B*s1.w;
    o1.x = g.B*s0.x + g.A*s1.x; o1.y = g.B*s0.y + g.A*s1.y;
    o1.z = g.B*s0.z + g.A*s1.z; o1.w = g.B*s0.w + g.A*s1.w;
    O[(size_t)zd * M4 + q] = o0;
    O[(size_t)(Dd + zd) * M4 + q] = o1;
}

// ---------------------------------------------------------------------------
// dev_k1_slice: fused W+H gaussian on one (H,W) slice, even (y,x) -> (Hd,Wd).
// Tile 64x16 in downsampled space.
__device__ void dev_k1_slice(const float* __restrict__ inA, float* __restrict__ out,
                             int x0d, int y0d, int slice, int H, int W, int Hd, int Wd,
                             const GW& g)
{
    __shared__ float raw[40][136];
    __shared__ float mid[40][64];
    const size_t in_off  = (size_t)slice * H * W;
    const size_t out_off = (size_t)slice * Hd * Wd;
    const int tid = threadIdx.x;
    const int gy0 = 2*y0d - 4, gx0 = 2*x0d - 4;
    if (2*x0d + 127 < W) {
        for (int i = tid; i < 40*32; i += 256) {
            int rr = i >> 5, c4 = (i & 31) + 1;
            int gy = ridx(gy0 + rr, H);
            *(float4*)&raw[rr][4*c4] =
                *(const float4*)(inA + in_off + (size_t)gy * W + gx0 + 4*c4);
        }
        for (int i = tid; i < 40*8; i += 256) {
            int rr = i >> 3, j = i & 7;
            int cc = (j < 4) ? j : (128 + j);
            int gy = ridx(gy0 + rr, H), gx = ridx(gx0 + cc, W);
            raw[rr][cc] = inA[in_off + (size_t)gy * W + gx];
        }
    } else {
        for (int i = tid; i < 40*136; i += 256) {
            int rr = i / 136, cc = i - rr*136;
            int gy = ridx(gy0 + rr, H), gx = ridx(gx0 + cc, W);
            raw[rr][cc] = inA[in_off + (size_t)gy * W + gx];
        }
    }
    __syncthreads();
    for (int i = tid; i < 40*64; i += 256) {
        int rr = i >> 6, c = i & 63;
        float s = 0.f;
        #pragma unroll
        for (int k = 0; k < 9; ++k) s = fmaf(g.w[k], raw[rr][2*c + k], s);
        mid[rr][c] = s;
    }
    __syncthreads();
    {
        int r = tid >> 6, c = tid & 63;
        int ox = x0d + c;
        #pragma unroll
        for (int j = 0; j < 4; ++j) {
            int oy = y0d + r*4 + j;
            if (oy < Hd && ox < Wd) {
                int rb = 2*(r*4 + j);
                float s = 0.f;
                #pragma unroll
                for (int k = 0; k < 9; ++k) s = fmaf(g.w[k], mid[rb + k][c], s);
                out[out_off + (size_t)oy * Wd + ox] = s;
            }
        }
    }
}

// ---------------------------------------------------------------------------
// dsall: the whole downsample ladder in one launch. 930 blocks:
// [0,512)   S0 k2l0 : T1 -> C1                 (signal ctr0)
// [512,768) k1s1    : C1 -> Tl1   wait ctr0==512, signal ctr1
// [768,832) k2s1    : Tl1 -> C2   wait ctr1==256, signal ctr2
// [832,896) k1s2    : C2 -> Tl2   wait ctr2==64,  signal ctr3
// [896,904) k2s2    : Tl2 -> C3   wait ctr3==64,  signal ctr4
// [904,920) k1s3    : C3 -> Tl3   wait ctr4==8,   signal ctr5
// [920,921) k2s3    : Tl3 -> C4   wait ctr5==16,  signal ctr6
// [921,929) k1s4    : C4 -> Tl4   wait ctr6==1,   signal ctr7
// [929,930) k2s4    : Tl4 -> C5   wait ctr7==8
struct DSP {
    const float* T1;
    float* C1; float* C2; float* C3; float* C4; float* C5;
    float* Tl1; float* Tl2; float* Tl3; float* Tl4;
    unsigned int* ctr;
    GW g;
};

__global__ __launch_bounds__(256, 4)   // >=4 blocks/CU -> all 930 co-resident
void dsall(DSP p)
{
    const int bid = (int)blockIdx.x, tid = threadIdx.x;
    const GW g = p.g;
    if (bid == 0 && tid == 0) p.ctr[9] = 0;   // k4p's completion counter
    if (bid < 512) {
        long i = (long)bid*256 + tid;
        dev_k2_elem(i, (const float4*)p.T1, (float4*)p.C1, 64, 32, 4096, g);
        signalctr(&p.ctr[0]);
    } else if (bid < 768) {
        waitctr(&p.ctr[0], 512);
        int local = bid - 512;
        int s = local >> 2, ty = local & 3;
        dev_k1_slice(p.C1, p.Tl1, 0, ty*16, s, 128, 128, 64, 64, g);
        signalctr(&p.ctr[1]);
    } else if (bid < 832) {
        waitctr(&p.ctr[1], 256);
        long i = (long)(bid - 768)*256 + tid;
        dev_k2_elem(i, (const float4*)p.Tl1, (float4*)p.C2, 32, 16, 1024, g);
        signalctr(&p.ctr[2]);
    } else if (bid < 896) {
        waitctr(&p.ctr[2], 64);
        int local = bid - 832;
        int s = local >> 1, ty = local & 1;
        dev_k1_slice(p.C2, p.Tl2, 0, ty*16, s, 64, 64, 32, 32, g);
        signalctr(&p.ctr[3]);
    } else if (bid < 904) {
        waitctr(&p.ctr[3], 64);
        long i = (long)(bid - 896)*256 + tid;
        dev_k2_elem(i, (const float4*)p.Tl2, (float4*)p.C3, 16, 8, 256, g);
        signalctr(&p.ctr[4]);
    } else if (bid < 920) {
        waitctr(&p.ctr[4], 8);
        dev_k1_slice(p.C3, p.Tl3, 0, 0, bid - 904, 32, 32, 16, 16, g);
        signalctr(&p.ctr[5]);
    } else if (bid < 921) {
        waitctr(&p.ctr[5], 16);
        dev_k2_elem((long)tid, (const float4*)p.Tl3, (float4*)p.C4, 8, 4, 64, g);
        signalctr(&p.ctr[6]);
    } else if (bid < 929) {
        waitctr(&p.ctr[6], 1);
        dev_k1_slice(p.C4, p.Tl4, 0, 0, bid - 921, 16, 16, 8, 8, g);
        signalctr(&p.ctr[7]);
    } else {
        waitctr(&p.ctr[7], 8);
        dev_k2_elem((long)tid, (const float4*)p.Tl4, (float4*)p.C5, 4, 2, 16, g);
    }
}

// ---------------------------------------------------------------------------
// k4p: ALL levels' loss. Per block one 64x32 tile; fuses on-the-fly z-filter+mix
// of dn (k3) with W/H up-filter + |cur - up| reduce. Last finisher reduces P.
struct K4P {
    const float* dn[5];
    const float* cur[5];
    const float* in; const float* tg;
    const __hip_bfloat16* DIFF;
    float* P; float* out;
    unsigned int* ctr;
    int use_diff; int np;
    int bo[6];
    GW g;
};

__global__ __launch_bounds__(256)
void k4p(K4P p)
{
    const int Dt[5] = {64,32,16,8,4}, Ht[5] = {256,128,64,32,16};
    __shared__ float vt[20][72];
    __shared__ float mid[20][64];
    const int bid = (int)blockIdx.x;
    int l = 0;
    while (l < 4 && bid >= p.bo[l+1]) ++l;
    const int local = bid - p.bo[l];
    const int D = Dt[l], H = Ht[l], W = H;
    const int Dd = D >> 1, Hd = H >> 1, Wd = W >> 1, Md = Hd * Wd;
    const int ntx = (W + 63) >> 6, nty = (H + 31) >> 5;
    const int s = local / (ntx*nty);
    const int rem = local - s*(ntx*nty);
    const int ty = rem / ntx, tx = rem - ty*ntx;
    const int x0 = tx*64, y0 = ty*32;
    const int b = s / D, z = s - b*D;
    const GW g = p.g;
    const float* dn0 = p.dn[l] + (size_t)b * Dd * Md;
    const float* dn1 = p.dn[l] + (size_t)(1 - b) * Dd * Md;
    const int tid = threadIdx.x;
    const int vy0 = (y0 >> 1) - 2;

    const bool zin = (z >= 4) && (z + 4 < D);
    if (zin && !(z & 1)) {
        const int j0 = (z >> 1) - 2;
        for (int i = tid; i < 20*72; i += 256) {
            int rr = i / 72, cc = i - rr*72;
            int vy = vy0 + rr;
            int txx = x0 - 4 + cc;
            if (txx < 0) txx = -1 - txx;
            float v = 0.f;
            if (vy >= 0 && vy < Hd && txx < Wd) {
                size_t o = (size_t)vy * Wd + txx;
                float s0 = 0.f, s1 = 0.f;
                #pragma unroll
                for (int t = 0; t < 5; ++t) {
                    s0 = fmaf(g.w[2*t], dn0[(size_t)(j0 + t) * Md + o], s0);
                    s1 = fmaf(g.w[2*t], dn1[(size_t)(j0 + t) * Md + o], s1);
                }
                v = 8.f * (g.A*s0 + g.B*s1);
            }
            vt[rr][cc] = v;
        }
    } else if (zin) {
        const int j0 = (z - 3) >> 1;
        for (int i = tid; i < 20*72; i += 256) {
            int rr = i / 72, cc = i - rr*72;
            int vy = vy0 + rr;
            int txx = x0 - 4 + cc;
            if (txx < 0) txx = -1 - txx;
            float v = 0.f;
            if (vy >= 0 && vy < Hd && txx < Wd) {
                size_t o = (size_t)vy * Wd + txx;
                float s0 = 0.f, s1 = 0.f;
                #pragma unroll
                for (int t = 0; t < 4; ++t) {
                    s0 = fmaf(g.w[2*t+1], dn0[(size_t)(j0 + t) * Md + o], s0);
                    s1 = fmaf(g.w[2*t+1], dn1[(size_t)(j0 + t) * Md + o], s1);
                }
                v = 8.f * (g.A*s0 + g.B*s1);
            }
            vt[rr][cc] = v;
        }
    } else {
        for (int i = tid; i < 20*72; i += 256) {
            int rr = i / 72, cc = i - rr*72;
            int vy = vy0 + rr;
            int txx = x0 - 4 + cc;
            if (txx < 0) txx = -1 - txx;
            float v = 0.f;
            if (vy >= 0 && vy < Hd && txx < Wd) {
                size_t o = (size_t)vy * Wd + txx;
                float s0 = 0.f, s1 = 0.f;
                #pragma unroll
                for (int k = 0; k < 9; ++k) {
                    int zk = ridx(z - 4 + k, D);
                    if (!(zk & 1)) {
                        int j = zk >> 1;
                        s0 = fmaf(g.w[k], dn0[(size_t)j * Md + o], s0);
                        s1 = fmaf(g.w[k], dn1[(size_t)j * Md + o], s1);
                    }
                }
                v = 8.f * (g.A*s0 + g.B*s1);
            }
            vt[rr][cc] = v;
        }
    }
    __syncthreads();
    for (int i = tid; i < 20*64; i += 256) {
        int rr = i >> 6, c = i & 63;
        float sv = 0.f;
        #pragma unroll
        for (int k = 0; k < 9; ++k) sv = fmaf(g.w[k], vt[rr][c + k], sv);
        mid[rr][c] = sv;
    }
    __syncthreads();
    const bool yin = (y0 >= 4) && (y0 + 35 < H);
    const int c = tid & 63;
    const int ry_base = (tid >> 6) * 8;
    const int ox = x0 + c;
    const size_t c_off = (size_t)s * H * W;
    const float* curl = (l >= 1) ? p.cur[l] : nullptr;
    float lsum = 0.f;
    #pragma unroll
    for (int j = 0; j < 8; ++j) {
        int ry = ry_base + j;
        int oy = y0 + ry;
        if (ox < W && oy < H) {
            float sv = 0.f;
            if (yin) {
                if (!(j & 1)) {
                    int r0 = ry >> 1;
                    sv = g.w[0]*mid[r0][c] + g.w[2]*mid[r0+1][c] + g.w[4]*mid[r0+2][c]
                       + g.w[6]*mid[r0+3][c] + g.w[8]*mid[r0+4][c];
                } else {
                    int r0 = ((ry - 3) >> 1) + 2;
                    sv = g.w[1]*mid[r0][c] + g.w[3]*mid[r0+1][c]
                       + g.w[5]*mid[r0+2][c] + g.w[7]*mid[r0+3][c];
                }
            } else {
                #pragma unroll
                for (int k = 0; k < 9; ++k) {
                    int gy = ridx(oy - 4 + k, H);
                    if (!(gy & 1)) sv = fmaf(g.w[k], mid[(gy >> 1) - vy0][c], sv);
                }
            }
            size_t idx = c_off + (size_t)oy * W + ox;
            float cv;
            if (l == 0) cv = p.use_diff ? __bfloat162float(p.DIFF[idx])
                                        : (p.in[idx] - p.tg[idx]);
            else        cv = curl[idx];
            lsum += fabsf(cv - sv);
        }
    }
    float tot = block_sum256(lsum);
    if (tid == 0) p.P[bid] = tot / ((float)(2*D) * H * W);

    // ---- last-finisher final reduce ----
    __threadfence();
    __syncthreads();
    __shared__ int lastflag;
    if (tid == 0) {
        unsigned int old = __hip_atomic_fetch_add(p.ctr + 9, 1u,
                              __ATOMIC_ACQ_REL, __HIP_MEMORY_SCOPE_AGENT);
        lastflag = (old == (unsigned int)(p.np - 1)) ? 1 : 0;
    }
    __syncthreads();
    if (lastflag) {
        float sacc = 0.f;
        for (int i = tid; i < p.np; i += 256) sacc += p.P[i];
        float t = block_sum256(sacc);
        if (tid == 0) p.out[0] = t;
    }
}

// ---------------------------------------------------------------------------
extern "C" void kernel_launch(void* const* d_in, const int* in_sizes, int n_in,
                              void* d_out, int out_size, void* d_ws, size_t ws_size,
                              hipStream_t stream)
{
    const float* in = (const float*)d_in[0];
    const float* tg = (const float*)d_in[1];
    float* out = (float*)d_out;

    GW g;
    {
        double u[9], S = 0.0;
        for (int k = 0; k < 9; ++k) { double d = k - 4; u[k] = exp(-0.5 * d * d); S += u[k]; }
        for (int k = 0; k < 9; ++k) g.w[k] = (float)(u[k] / S);
        g.A = (float)((2.0*u[0] + u[1] + u[3] + u[4]) / S);  // batch(2) reflect self-weight
        g.B = (float)((u[1] + 2.0*u[2] + u[3]) / S);         // cross-weight
    }

    // workspace layout: [64 uint ctrs][floats...][bf16 DIFF]
    unsigned int* ctr = (unsigned int*)d_ws;
    float* T1  = (float*)d_ws + 64;        // 2*64*128*128 = 2097152
    float* C1  = T1  + 2097152;            // 2*32*128*128 = 1048576
    float* C2  = C1  + 1048576;            // 2*16*64*64   = 131072
    float* C3  = C2  + 131072;             // 2*8*32*32    = 16384
    float* C4  = C3  + 16384;              // 2*4*16*16    = 2048
    float* C5  = C4  + 2048;               // 2*2*8*8      = 256
    float* Tl1 = C5  + 256;                // 2*32*64*64   = 262144
    float* Tl2 = Tl1 + 262144;             // 2*16*32*32   = 32768
    float* Tl3 = Tl2 + 32768;              // 2*8*16*16    = 4096
    float* Tl4 = Tl3 + 4096;               // 2*4*8*8      = 512
    float* P   = Tl4 + 512;                // 8192 partial slots
    float* wend = P + 8192;
    __hip_bfloat16* DIFF = (__hip_bfloat16*)wend;
    const size_t base_bytes = (size_t)((char*)wend - (char*)d_ws);
    const size_t diff_bytes = (size_t)2 * 64 * 256 * 256 * sizeof(__hip_bfloat16);
    const int use_diff = (ws_size >= base_bytes + diff_bytes) ? 1 : 0;

    dim3 blk(256);

    // D1: k1l0 (+DIFF, zero ctrs)
    if (use_diff) k1l0<true ><<<dim3(2,8,128), blk, 0, stream>>>(in, tg, T1, DIFF, ctr, g);
    else          k1l0<false><<<dim3(2,8,128), blk, 0, stream>>>(in, tg, T1, nullptr, ctr, g);

    // D2: whole downsample ladder
    DSP dp;
    dp.T1 = T1; dp.C1 = C1; dp.C2 = C2; dp.C3 = C3; dp.C4 = C4; dp.C5 = C5;
    dp.Tl1 = Tl1; dp.Tl2 = Tl2; dp.Tl3 = Tl3; dp.Tl4 = Tl4;
    dp.ctr = ctr; dp.g = g;
    dsall<<<dim3(930), blk, 0, stream>>>(dp);

    // D3: all levels' loss + final reduce
    K4P prm;
    prm.dn[0] = C1; prm.dn[1] = C2; prm.dn[2] = C3; prm.dn[3] = C4; prm.dn[4] = C5;
    prm.cur[0] = nullptr; prm.cur[1] = C1; prm.cur[2] = C2; prm.cur[3] = C3; prm.cur[4] = C4;
    prm.in = in; prm.tg = tg;
    prm.DIFF = use_diff ? DIFF : nullptr;
    prm.P = P; prm.out = out; prm.ctr = ctr;
    prm.use_diff = use_diff; prm.np = 4696;
    prm.g = g;
    prm.bo[0] = 0; prm.bo[1] = 4096; prm.bo[2] = 4608;
    prm.bo[3] = 4672; prm.bo[4] = 4688; prm.bo[5] = 4696;
    k4p<<<dim3(4696), blk, 0, stream>>>(prm);
}

// Round 8
// 119.213 us; speedup vs baseline: 5.5814x; 5.5814x over previous
//
#include <hip/hip_runtime.h>
#include <hip/hip_bf16.h>
#include <math.h>

// Laplacian-pyramid L1 loss, (2,1,64,256,256), 5 levels, sigma=1 (9-tap), scipy-reflect.
// loss = sum_l mean |lap_pyramid(input-target)[l]| (linearity of the pyramid).
// 12 plain launches, no cross-block sync (agent-scope fences are ~0.1us each on
// gfx950's non-coherent XCDs -- rounds 5/7 proved them catastrophic):
//   k1l0(+bf16 DIFF) -> k2l0 -> {k1s,k2s} x levels 1..4 -> k4p(all) -> kreduce.

struct GW { float w[9]; float A, B; };

__device__ __forceinline__ int ridx(int p, int n) {
    // scipy 'reflect' (symmetric) for power-of-two n; valid for p >= -2n
    int m = 2 * n;
    int q = (p + m) & (m - 1);
    return (q < n) ? q : (m - 1 - q);
}

__device__ __forceinline__ float block_sum256(float v) {
    #pragma unroll
    for (int off = 32; off > 0; off >>= 1) v += __shfl_down(v, off, 64);
    __shared__ float wp[4];
    int tid = threadIdx.x;
    if ((tid & 63) == 0) wp[tid >> 6] = v;
    __syncthreads();
    return wp[0] + wp[1] + wp[2] + wp[3];
}

// ---------------------------------------------------------------------------
// k1l0: level-0 fused W+H gaussian of (in - tg), emitting even (y,x) -> T1.
// Optionally writes bf16 DIFF = in - tg. Tile 64x16 downsampled; grid (2,8,128).
template<bool WDIFF>
__global__ __launch_bounds__(256)
void k1l0(const float* __restrict__ in, const float* __restrict__ tg,
          float* __restrict__ T1, __hip_bfloat16* __restrict__ DIFF, GW g)
{
    const int H = 256, W = 256, Wd = 128;
    const int x0d = blockIdx.x * 64, y0d = blockIdx.y * 16, slice = blockIdx.z;
    __shared__ float raw[40][136];
    __shared__ float mid[40][64];
    const size_t in_off  = (size_t)slice * H * W;
    const size_t out_off = (size_t)slice * 128 * 128;
    const int tid = threadIdx.x;
    const int gy0 = 2*y0d - 4, gx0 = 2*x0d - 4;
    for (int i = tid; i < 40*32; i += 256) {
        int rr = i >> 5, c4 = (i & 31) + 1;
        int gy = ridx(gy0 + rr, H);
        size_t base = in_off + (size_t)gy * W + gx0 + 4*c4;
        float4 v = *(const float4*)(in + base);
        float4 b = *(const float4*)(tg + base);
        v.x -= b.x; v.y -= b.y; v.z -= b.z; v.w -= b.w;
        *(float4*)&raw[rr][4*c4] = v;
    }
    for (int i = tid; i < 40*8; i += 256) {
        int rr = i >> 3, j = i & 7;
        int cc = (j < 4) ? j : (128 + j);
        int gy = ridx(gy0 + rr, H);
        int gx = ridx(gx0 + cc, W);
        size_t idx = in_off + (size_t)gy * W + gx;
        raw[rr][cc] = in[idx] - tg[idx];
    }
    __syncthreads();
    if (WDIFF) {
        for (int i = tid; i < 32*128; i += 256) {
            int r = i >> 7, c = i & 127;
            DIFF[in_off + (size_t)(2*y0d + r) * W + (2*x0d + c)] =
                __float2bfloat16(raw[4 + r][4 + c]);
        }
    }
    for (int i = tid; i < 40*64; i += 256) {
        int rr = i >> 6, c = i & 63;
        float s = 0.f;
        #pragma unroll
        for (int k = 0; k < 9; ++k) s = fmaf(g.w[k], raw[rr][2*c + k], s);
        mid[rr][c] = s;
    }
    __syncthreads();
    {
        int r = tid >> 6, c = tid & 63;
        int ox = x0d + c;
        #pragma unroll
        for (int j = 0; j < 4; ++j) {
            int oy = y0d + r*4 + j;
            int rb = 2*(r*4 + j);
            float s = 0.f;
            #pragma unroll
            for (int k = 0; k < 9; ++k) s = fmaf(g.w[k], mid[rb + k][c], s);
            T1[out_off + (size_t)oy * Wd + ox] = s;
        }
    }
}

// ---------------------------------------------------------------------------
// k2s: D-axis gaussian + batch(2) reflect mix at even z. One float4/elem.
__global__ __launch_bounds__(256)
void k2s(const float* __restrict__ Tin, float* __restrict__ Cout,
         int D, int Dd, int M4, GW g)
{
    long i = (long)blockIdx.x * 256 + threadIdx.x;
    if (i >= (long)Dd * M4) return;
    int zd = (int)(i / M4);
    int q  = (int)(i - (long)zd * M4);
    const float4* T = (const float4*)Tin;
    float4* O = (float4*)Cout;
    float4 s0 = {0,0,0,0}, s1 = {0,0,0,0};
    #pragma unroll
    for (int k = 0; k < 9; ++k) {
        int zp = 2*zd - 4 + k;
        int zk = (zp >= 0 && zp < D) ? zp : ridx(zp, D);
        float4 a = T[(size_t)zk * M4 + q];
        float4 b = T[(size_t)(D + zk) * M4 + q];
        s0.x = fmaf(g.w[k], a.x, s0.x); s0.y = fmaf(g.w[k], a.y, s0.y);
        s0.z = fmaf(g.w[k], a.z, s0.z); s0.w = fmaf(g.w[k], a.w, s0.w);
        s1.x = fmaf(g.w[k], b.x, s1.x); s1.y = fmaf(g.w[k], b.y, s1.y);
        s1.z = fmaf(g.w[k], b.z, s1.z); s1.w = fmaf(g.w[k], b.w, s1.w);
    }
    float4 o0, o1;
    o0.x = g.A*s0.x + g.B*s1.x; o0.y = g.A*s0.y + g.B*s1.y;
    o0.z = g.A*s0.z + g.B*s1.z; o0.w = g.A*s0.w + g.B*s1.w;
    o1.x = g.B*s0.x + g.A*s1.x; o1.y = g.B*s0.y + g.A*s1.y;
    o1.z = g.B*s0.z + g.A*s1.z; o1.w = g.B*s0.w + g.A*s1.w;
    O[(size_t)zd * M4 + q] = o0;
    O[(size_t)(Dd + zd) * M4 + q] = o1;
}

// ---------------------------------------------------------------------------
// k1s: fused W+H gaussian on one (H,W) slice, even (y,x) -> (Hd,Wd).
// Tile 64x16 in downsampled space. grid (ntx, nty, slices).
__global__ __launch_bounds__(256)
void k1s(const float* __restrict__ inA, float* __restrict__ out,
         int H, int W, int Hd, int Wd, GW g)
{
    const int x0d = blockIdx.x * 64, y0d = blockIdx.y * 16, slice = blockIdx.z;
    __shared__ float raw[40][136];
    __shared__ float mid[40][64];
    const size_t in_off  = (size_t)slice * H * W;
    const size_t out_off = (size_t)slice * Hd * Wd;
    const int tid = threadIdx.x;
    const int gy0 = 2*y0d - 4, gx0 = 2*x0d - 4;
    if (2*x0d + 127 < W) {
        for (int i = tid; i < 40*32; i += 256) {
            int rr = i >> 5, c4 = (i & 31) + 1;
            int gy = ridx(gy0 + rr, H);
            *(float4*)&raw[rr][4*c4] =
                *(const float4*)(inA + in_off + (size_t)gy * W + gx0 + 4*c4);
        }
        for (int i = tid; i < 40*8; i += 256) {
            int rr = i >> 3, j = i & 7;
            int cc = (j < 4) ? j : (128 + j);
            int gy = ridx(gy0 + rr, H), gx = ridx(gx0 + cc, W);
            raw[rr][cc] = inA[in_off + (size_t)gy * W + gx];
        }
    } else {
        for (int i = tid; i < 40*136; i += 256) {
            int rr = i / 136, cc = i - rr*136;
            int gy = ridx(gy0 + rr, H), gx = ridx(gx0 + cc, W);
            raw[rr][cc] = inA[in_off + (size_t)gy * W + gx];
        }
    }
    __syncthreads();
    for (int i = tid; i < 40*64; i += 256) {
        int rr = i >> 6, c = i & 63;
        float s = 0.f;
        #pragma unroll
        for (int k = 0; k < 9; ++k) s = fmaf(g.w[k], raw[rr][2*c + k], s);
        mid[rr][c] = s;
    }
    __syncthreads();
    {
        int r = tid >> 6, c = tid & 63;
        int ox = x0d + c;
        #pragma unroll
        for (int j = 0; j < 4; ++j) {
            int oy = y0d + r*4 + j;
            if (oy < Hd && ox < Wd) {
                int rb = 2*(r*4 + j);
                float s = 0.f;
                #pragma unroll
                for (int k = 0; k < 9; ++k) s = fmaf(g.w[k], mid[rb + k][c], s);
                out[out_off + (size_t)oy * Wd + ox] = s;
            }
        }
    }
}

// ---------------------------------------------------------------------------
// k4p: ALL levels' loss. Per block one 64x32 tile; fuses on-the-fly z-filter+mix
// of dn (the upsample D/batch part) with W/H up-filter + |cur - up| reduce.
struct K4P {
    const float* dn[5];
    const float* cur[5];
    const float* in; const float* tg;
    const __hip_bfloat16* DIFF;
    float* P;
    int use_diff;
    int bo[6];
    GW g;
};

__global__ __launch_bounds__(256)
void k4p(K4P p)
{
    const int Dt[5] = {64,32,16,8,4}, Ht[5] = {256,128,64,32,16};
    __shared__ float vt[20][72];
    __shared__ float mid[20][64];
    const int bid = (int)blockIdx.x;
    int l = 0;
    while (l < 4 && bid >= p.bo[l+1]) ++l;
    const int local = bid - p.bo[l];
    const int D = Dt[l], H = Ht[l], W = H;
    const int Dd = D >> 1, Hd = H >> 1, Wd = W >> 1, Md = Hd * Wd;
    const int ntx = (W + 63) >> 6, nty = (H + 31) >> 5;
    const int s = local / (ntx*nty);
    const int rem = local - s*(ntx*nty);
    const int ty = rem / ntx, tx = rem - ty*ntx;
    const int x0 = tx*64, y0 = ty*32;
    const int b = s / D, z = s - b*D;
    const GW g = p.g;
    const float* dn0 = p.dn[l] + (size_t)b * Dd * Md;
    const float* dn1 = p.dn[l] + (size_t)(1 - b) * Dd * Md;
    const int tid = threadIdx.x;
    const int vy0 = (y0 >> 1) - 2;

    const bool zin = (z >= 4) && (z + 4 < D);
    if (zin && !(z & 1)) {
        const int j0 = (z >> 1) - 2;
        for (int i = tid; i < 20*72; i += 256) {
            int rr = i / 72, cc = i - rr*72;
            int vy = vy0 + rr;
            int txx = x0 - 4 + cc;
            if (txx < 0) txx = -1 - txx;
            float v = 0.f;
            if (vy >= 0 && vy < Hd && txx < Wd) {
                size_t o = (size_t)vy * Wd + txx;
                float s0 = 0.f, s1 = 0.f;
                #pragma unroll
                for (int t = 0; t < 5; ++t) {
                    s0 = fmaf(g.w[2*t], dn0[(size_t)(j0 + t) * Md + o], s0);
                    s1 = fmaf(g.w[2*t], dn1[(size_t)(j0 + t) * Md + o], s1);
                }
                v = 8.f * (g.A*s0 + g.B*s1);
            }
            vt[rr][cc] = v;
        }
    } else if (zin) {
        const int j0 = (z - 3) >> 1;
        for (int i = tid; i < 20*72; i += 256) {
            int rr = i / 72, cc = i - rr*72;
            int vy = vy0 + rr;
            int txx = x0 - 4 + cc;
            if (txx < 0) txx = -1 - txx;
            float v = 0.f;
            if (vy >= 0 && vy < Hd && txx < Wd) {
                size_t o = (size_t)vy * Wd + txx;
                float s0 = 0.f, s1 = 0.f;
                #pragma unroll
                for (int t = 0; t < 4; ++t) {
                    s0 = fmaf(g.w[2*t+1], dn0[(size_t)(j0 + t) * Md + o], s0);
                    s1 = fmaf(g.w[2*t+1], dn1[(size_t)(j0 + t) * Md + o], s1);
                }
                v = 8.f * (g.A*s0 + g.B*s1);
            }
            vt[rr][cc] = v;
        }
    } else {
        for (int i = tid; i < 20*72; i += 256) {
            int rr = i / 72, cc = i - rr*72;
            int vy = vy0 + rr;
            int txx = x0 - 4 + cc;
            if (txx < 0) txx = -1 - txx;
            float v = 0.f;
            if (vy >= 0 && vy < Hd && txx < Wd) {
                size_t o = (size_t)vy * Wd + txx;
                float s0 = 0.f, s1 = 0.f;
                #pragma unroll
                for (int k = 0; k < 9; ++k) {
                    int zk = ridx(z - 4 + k, D);
                    if (!(zk & 1)) {
                        int j = zk >> 1;
                        s0 = fmaf(g.w[k], dn0[(size_t)j * Md + o], s0);
                        s1 = fmaf(g.w[k], dn1[(size_t)j * Md + o], s1);
                    }
                }
                v = 8.f * (g.A*s0 + g.B*s1);
            }
            vt[rr][cc] = v;
        }
    }
    __syncthreads();
    for (int i = tid; i < 20*64; i += 256) {
        int rr = i >> 6, c = i & 63;
        float sv = 0.f;
        #pragma unroll
        for (int k = 0; k < 9; ++k) sv = fmaf(g.w[k], vt[rr][c + k], sv);
        mid[rr][c] = sv;
    }
    __syncthreads();
    const bool yin = (y0 >= 4) && (y0 + 35 < H);
    const int c = tid & 63;
    const int ry_base = (tid >> 6) * 8;
    const int ox = x0 + c;
    const size_t c_off = (size_t)s * H * W;
    const float* curl = (l >= 1) ? p.cur[l] : nullptr;
    float lsum = 0.f;
    #pragma unroll
    for (int j = 0; j < 8; ++j) {
        int ry = ry_base + j;
        int oy = y0 + ry;
        if (ox < W && oy < H) {
            float sv = 0.f;
            if (yin) {
                if (!(j & 1)) {
                    int r0 = ry >> 1;
                    sv = g.w[0]*mid[r0][c] + g.w[2]*mid[r0+1][c] + g.w[4]*mid[r0+2][c]
                       + g.w[6]*mid[r0+3][c] + g.w[8]*mid[r0+4][c];
                } else {
                    int r0 = ((ry - 3) >> 1) + 2;
                    sv = g.w[1]*mid[r0][c] + g.w[3]*mid[r0+1][c]
                       + g.w[5]*mid[r0+2][c] + g.w[7]*mid[r0+3][c];
                }
            } else {
                #pragma unroll
                for (int k = 0; k < 9; ++k) {
                    int gy = ridx(oy - 4 + k, H);
                    if (!(gy & 1)) sv = fmaf(g.w[k], mid[(gy >> 1) - vy0][c], sv);
                }
            }
            size_t idx = c_off + (size_t)oy * W + ox;
            float cv;
            if (l == 0) cv = p.use_diff ? __bfloat162float(p.DIFF[idx])
                                        : (p.in[idx] - p.tg[idx]);
            else        cv = curl[idx];
            lsum += fabsf(cv - sv);
        }
    }
    float tot = block_sum256(lsum);
    if (tid == 0) p.P[bid] = tot / ((float)(2*D) * H * W);
}

// ---------------------------------------------------------------------------
__global__ __launch_bounds__(1024)
void kreduce(const float* __restrict__ P, int n, float* __restrict__ out)
{
    float s = 0.f;
    for (int i = threadIdx.x; i < n; i += 1024) s += P[i];
    #pragma unroll
    for (int off = 32; off > 0; off >>= 1) s += __shfl_down(s, off, 64);
    __shared__ float wp[16];
    if ((threadIdx.x & 63) == 0) wp[threadIdx.x >> 6] = s;
    __syncthreads();
    if (threadIdx.x == 0) {
        float t = 0.f;
        #pragma unroll
        for (int w = 0; w < 16; ++w) t += wp[w];
        out[0] = t;
    }
}

// ---------------------------------------------------------------------------
extern "C" void kernel_launch(void* const* d_in, const int* in_sizes, int n_in,
                              void* d_out, int out_size, void* d_ws, size_t ws_size,
                              hipStream_t stream)
{
    const float* in = (const float*)d_in[0];
    const float* tg = (const float*)d_in[1];
    float* out = (float*)d_out;

    GW g;
    {
        double u[9], S = 0.0;
        for (int k = 0; k < 9; ++k) { double d = k - 4; u[k] = exp(-0.5 * d * d); S += u[k]; }
        for (int k = 0; k < 9; ++k) g.w[k] = (float)(u[k] / S);
        g.A = (float)((2.0*u[0] + u[1] + u[3] + u[4]) / S);  // batch(2) reflect self-weight
        g.B = (float)((u[1] + 2.0*u[2] + u[3]) / S);         // cross-weight
    }

    // workspace layout (floats)
    float* T1  = (float*)d_ws;             // 2*64*128*128 = 2097152
    float* C1  = T1  + 2097152;            // 2*32*128*128 = 1048576
    float* C2  = C1  + 1048576;            // 2*16*64*64   = 131072
    float* C3  = C2  + 131072;             // 2*8*32*32    = 16384
    float* C4  = C3  + 16384;              // 2*4*16*16    = 2048
    float* C5  = C4  + 2048;               // 2*2*8*8      = 256
    float* Tl1 = C5  + 256;                // 2*32*64*64   = 262144
    float* Tl2 = Tl1 + 262144;             // 2*16*32*32   = 32768
    float* Tl3 = Tl2 + 32768;              // 2*8*16*16    = 4096
    float* Tl4 = Tl3 + 4096;               // 2*4*8*8      = 512
    float* P   = Tl4 + 512;                // 8192 partial slots
    float* wend = P + 8192;
    __hip_bfloat16* DIFF = (__hip_bfloat16*)wend;
    const size_t base_bytes = (size_t)((char*)wend - (char*)d_ws);
    const size_t diff_bytes = (size_t)2 * 64 * 256 * 256 * sizeof(__hip_bfloat16);
    const int use_diff = (ws_size >= base_bytes + diff_bytes) ? 1 : 0;

    dim3 blk(256);

    // D1: level-0 WH-down of diff (+ bf16 DIFF)
    if (use_diff) k1l0<true ><<<dim3(2,8,128), blk, 0, stream>>>(in, tg, T1, DIFF, g);
    else          k1l0<false><<<dim3(2,8,128), blk, 0, stream>>>(in, tg, T1, nullptr, g);

    // D2: k2(0): T1 -> C1  (D=64, Dd=32, M4=128*128/4=4096)
    k2s<<<dim3(512), blk, 0, stream>>>(T1, C1, 64, 32, 4096, g);

    // D3-D10: small ladder (all plain, fully parallel kernels)
    k1s<<<dim3(1,4,64), blk, 0, stream>>>(C1, Tl1, 128, 128, 64, 64, g);
    k2s<<<dim3(64),     blk, 0, stream>>>(Tl1, C2, 32, 16, 1024, g);
    k1s<<<dim3(1,2,32), blk, 0, stream>>>(C2, Tl2, 64, 64, 32, 32, g);
    k2s<<<dim3(8),      blk, 0, stream>>>(Tl2, C3, 16, 8, 256, g);
    k1s<<<dim3(1,1,16), blk, 0, stream>>>(C3, Tl3, 32, 32, 16, 16, g);
    k2s<<<dim3(1),      blk, 0, stream>>>(Tl3, C4, 8, 4, 64, g);
    k1s<<<dim3(1,1,8),  blk, 0, stream>>>(C4, Tl4, 16, 16, 8, 8, g);
    k2s<<<dim3(1),      blk, 0, stream>>>(Tl4, C5, 4, 2, 16, g);

    // D11: all levels' loss
    K4P prm;
    prm.dn[0] = C1; prm.dn[1] = C2; prm.dn[2] = C3; prm.dn[3] = C4; prm.dn[4] = C5;
    prm.cur[0] = nullptr; prm.cur[1] = C1; prm.cur[2] = C2; prm.cur[3] = C3; prm.cur[4] = C4;
    prm.in = in; prm.tg = tg;
    prm.DIFF = use_diff ? DIFF : nullptr;
    prm.P = P; prm.use_diff = use_diff;
    prm.g = g;
    prm.bo[0] = 0; prm.bo[1] = 4096; prm.bo[2] = 4608;
    prm.bo[3] = 4672; prm.bo[4] = 4688; prm.bo[5] = 4696;
    k4p<<<dim3(4696), blk, 0, stream>>>(prm);

    // D12: final reduce
    kreduce<<<1, 1024, 0, stream>>>(P, 4696, out);
}